// Round 8
// baseline (283.279 us; speedup 1.0000x reference)
//
#include <hip/hip_runtime.h>
#include <hip/hip_fp16.h>

// PhotometricLoss: total = 0.8*L1 + 0.2*DSSIM; fused separable 11x11 Gaussian
// SSIM, SAME zero padding. Inputs BHWC fp32 (B=4,H=1080,W=1920,C=3).
// R8: plane-interleaved uint4 LDS layouts -> LDS instrs 72 -> ~29/thread:
// stage 1x b128/item; h-pass reads 4 planes per b128, item = (row-pair, 2
// cols) so transposed result is 1x b128/col; v-pass reads 7x b128 (each =
// 4 dot2-ready row-pairs). LDS 14.8KB, 8 blocks/CU.

typedef _Float16 h2_t __attribute__((ext_vector_type(2)));

#define TW 32
#define TH 32
#define IH 42         // tile rows incl halo
#define NPAIR 21      // column pairs (42 cols)
#define SPW 22        // sP4 row stride in uint4 (352B rows)
#define HCS 22        // hcT2 col stride in uint4 (21 row-pairs + pad)
#define NSLOT 512

#define HH 1080
#define WW 1920
#define GX 180        // (WW/TW)*3 channels
#define GY 34         // ceil(HH/TH)

// Gaussian(sigma=1.5, 11 taps), normalized; matches fp32 reference within ~2e-7
static constexpr float G[11] = {
    0.00102838f, 0.00759876f, 0.03600077f, 0.10936069f, 0.21300554f,
    0.26601174f, 0.21300554f, 0.10936069f, 0.03600077f, 0.00759876f,
    0.00102838f};

#define WV(m) (((m) >= 0 && (m) <= 10) ? G[((m) < 0) ? 0 : (((m) > 10) ? 10 : (m))] : 0.0f)

struct f4u { float x, y, z, w; } __attribute__((packed, aligned(4)));

__device__ __forceinline__ unsigned short f2hbits(float x) {
    return __half_as_ushort(__float2half(x));
}
__device__ __forceinline__ unsigned int pkrtz(float a, float b) {
    return __builtin_bit_cast(unsigned int, __builtin_amdgcn_cvt_pkrtz(a, b));
}
__device__ __forceinline__ float dot2h(unsigned int a, unsigned int b, float c) {
#if __has_builtin(__builtin_amdgcn_fdot2)
    return __builtin_amdgcn_fdot2(__builtin_bit_cast(h2_t, a),
                                  __builtin_bit_cast(h2_t, b), c, false);
#else
    h2_t ah = __builtin_bit_cast(h2_t, a), bh = __builtin_bit_cast(h2_t, b);
    return c + (float)ah[0] * (float)bh[0] + (float)ah[1] * (float)bh[1];
#endif
}

// h-pass item = (row-pair rp, output cols cb..cb+1), all 4 planes.
// Reads 12x b128 (6 pairs x 2 rows), returns 2x uint4 packed for hcT2:
// o[u] = halves {q0e0,q0e1, q1e0,q1e1, q2e0,q2e1, q3e0,q3e1} for col cb+u.
__device__ __forceinline__ void h_item2p(const uint4* __restrict__ sP4,
                                         int t, uint4 o[2]) {
    int rp = t >> 4;
    int p0 = t & 15;
    float a[2][2][4];
    #pragma unroll
    for (int e = 0; e < 2; ++e)
        #pragma unroll
        for (int u = 0; u < 2; ++u)
            #pragma unroll
            for (int q = 0; q < 4; ++q) a[e][u][q] = 0.f;
    #pragma unroll
    for (int e = 0; e < 2; ++e) {
        const uint4* sp = sP4 + (2 * rp + e) * SPW + p0;
        uint4 v[6];
        #pragma unroll
        for (int p = 0; p < 6; ++p) v[p] = sp[p];
        #pragma unroll
        for (int u = 0; u < 2; ++u) {
            #pragma unroll
            for (int p = 0; p < 6; ++p) {
                const float w0 = WV(2 * p - u), w1 = WV(2 * p + 1 - u);
                if (w0 != 0.f || w1 != 0.f) {
                    const unsigned gwc = (unsigned)f2hbits(w0) |
                                         ((unsigned)f2hbits(w1) << 16);
                    a[e][u][0] = dot2h(v[p].x, gwc, a[e][u][0]);
                    a[e][u][1] = dot2h(v[p].y, gwc, a[e][u][1]);
                    a[e][u][2] = dot2h(v[p].z, gwc, a[e][u][2]);
                    a[e][u][3] = dot2h(v[p].w, gwc, a[e][u][3]);
                }
            }
        }
    }
    #pragma unroll
    for (int u = 0; u < 2; ++u) {
        o[u].x = pkrtz(a[0][u][0], a[1][u][0]);
        o[u].y = pkrtz(a[0][u][1], a[1][u][1]);
        o[u].z = pkrtz(a[0][u][2], a[1][u][2]);
        o[u].w = pkrtz(a[0][u][3], a[1][u][3]);
    }
}
__device__ __forceinline__ void h_write2(uint4* __restrict__ hcT2,
                                         int t, const uint4 o[2]) {
    int rp = t >> 4;
    int cb = (t & 15) << 1;
    hcT2[(cb + 0) * HCS + rp] = o[0];
    hcT2[(cb + 1) * HCS + rp] = o[1];
}

__global__ __launch_bounds__(256, 8) void photo_main(
    const float* __restrict__ xin, const float* __restrict__ yin,
    double* __restrict__ accum, int B, int nwg)
{
    __shared__ uint4 sP4[IH * SPW];   // 14784 B; hcT2 aliases this after barrier
    __shared__ float red[8];

    // ---- bijective XCD swizzle (nwg % 8 == 0), channel fastest in x
    int orig = blockIdx.x + GX * (blockIdx.y + GY * blockIdx.z);
    int nid = ((nwg & 7) == 0) ? ((orig & 7) * (nwg >> 3) + (orig >> 3)) : orig;
    int bx   = nid % GX;
    int rest = nid / GX;
    int by   = rest % GY;
    int b    = rest / GY;
    int c    = bx % 3;
    int tx   = bx / 3;
    const int row0 = by * TH, col0 = tx * TW;
    const int tid  = threadIdx.x;
    const int imgbase = b * (HH * WW * 3) + c;

    // ---- Phase 1a: stage 4 packed fp16 moment planes {x,y,x2+y2,xy} as ONE
    // uint4 per (row, col-pair); fold L1 over the central 32x32.
    float l1_sum = 0.f;
    const bool interior = (tx >= 1) && (tx <= 58) && (by >= 1) && (by <= 32);
    if (interior) {
        for (int i = tid; i < IH * NPAIR; i += 256) {
            int r  = i / NPAIR;
            int pc = i - r * NPAIR;
            int gr  = row0 - 5 + r;
            int gc0 = col0 - 5 + 2 * pc;
            int base = imgbase + (gr * WW + gc0) * 3;
            f4u vx = *(const f4u*)&xin[base];     // x0 = .x, x1 = .w (stride-3)
            f4u vy = *(const f4u*)&yin[base];
            float x0 = vx.x, x1 = vx.w, y0 = vy.x, y1 = vy.w;
            uint4 w;
            w.x = pkrtz(x0, x1);
            w.y = pkrtz(y0, y1);
            w.z = pkrtz(fmaf(x0, x0, y0 * y0), fmaf(x1, x1, y1 * y1));
            w.w = pkrtz(x0 * y0, x1 * y1);
            sP4[r * SPW + pc] = w;
            if (r >= 5 && r < 5 + TH) {
                if (pc >= 3 && pc <= 18) l1_sum += fabsf(x0 - y0);
                if (pc >= 2 && pc <= 17) l1_sum += fabsf(x1 - y1);
            }
        }
    } else {
        #pragma unroll 1
        for (int i = tid; i < IH * NPAIR; i += 256) {
            int r  = i / NPAIR;
            int pc = i - r * NPAIR;
            int gr  = row0 - 5 + r;
            int gc0 = col0 - 5 + 2 * pc;
            bool rin = (unsigned)gr < (unsigned)HH;
            bool c0  = rin && ((unsigned)gc0       < (unsigned)WW);
            bool c1  = rin && ((unsigned)(gc0 + 1) < (unsigned)WW);
            int base = imgbase + (gr * WW + gc0) * 3;
            float x0 = 0.f, x1 = 0.f, y0 = 0.f, y1 = 0.f;
            if (c0) { x0 = xin[base];     y0 = yin[base]; }
            if (c1) { x1 = xin[base + 3]; y1 = yin[base + 3]; }
            uint4 w;
            w.x = pkrtz(x0, x1);
            w.y = pkrtz(y0, y1);
            w.z = pkrtz(fmaf(x0, x0, y0 * y0), fmaf(x1, x1, y1 * y1));
            w.w = pkrtz(x0 * y0, x1 * y1);
            sP4[r * SPW + pc] = w;
            if (r >= 5 && r < 5 + TH) {
                if (c0 && pc >= 3 && pc <= 18) l1_sum += fabsf(x0 - y0);
                if (c1 && pc >= 2 && pc <= 17) l1_sum += fabsf(x1 - y1);
            }
        }
    }
    __syncthreads();

    // ---- Phase 1b: h-conv all planes; 336 items = (row-pair, 2 cols) on 256
    // threads (tid, plus tid+256 iff tid < 80). Read all -> pack -> barrier ->
    // write transposed hcT2 over the same LDS -> barrier.
    uint4* hcT2 = (uint4*)sP4;     // 32 cols * HCS * 16B = 11264 B, aliased
    {
        const bool has2 = tid < (IH / 2 * 16 - 256);   // 336 - 256 = 80
        uint4 o0[2], o1[2];
        h_item2p(sP4, tid, o0);
        if (has2) h_item2p(sP4, tid + 256, o1);
        __syncthreads();
        h_write2(hcT2, tid, o0);
        if (has2) h_write2(hcT2, tid + 256, o1);
        __syncthreads();
    }

    // ---- Phase 2: vertical conv via dot2; each b128 read = one row-pair of
    // all 4 planes, dot2-ready.
    const float C1c = 1e-4f, C2c = 9e-4f;
    float ssim_sum = 0.f;
    {
        int cc = tid & 31;
        int rb = (tid >> 5) << 2;          // output row base within tile
        const uint4* hp = hcT2 + cc * HCS + (rb >> 1);
        uint4 v[7];
        #pragma unroll
        for (int p = 0; p < 7; ++p) v[p] = hp[p];
        float acc[4][4];                   // [u][q]
        #pragma unroll
        for (int u = 0; u < 4; ++u)
            #pragma unroll
            for (int q = 0; q < 4; ++q) acc[u][q] = 0.f;
        #pragma unroll
        for (int u = 0; u < 4; ++u) {
            #pragma unroll
            for (int p = 0; p < 7; ++p) {
                const float w0 = WV(2 * p - u), w1 = WV(2 * p + 1 - u);
                if (w0 != 0.f || w1 != 0.f) {
                    const unsigned gwc = (unsigned)f2hbits(w0) |
                                         ((unsigned)f2hbits(w1) << 16);
                    acc[u][0] = dot2h(v[p].x, gwc, acc[u][0]);
                    acc[u][1] = dot2h(v[p].y, gwc, acc[u][1]);
                    acc[u][2] = dot2h(v[p].z, gwc, acc[u][2]);
                    acc[u][3] = dot2h(v[p].w, gwc, acc[u][3]);
                }
            }
        }
        #pragma unroll
        for (int u = 0; u < 4; ++u) {
            int gr = row0 + rb + u;
            if (gr < HH) {                 // cols always in range (WW % 32 == 0)
                float mu1 = acc[u][0], mu2 = acc[u][1];
                float mu1s = mu1 * mu1, mu2s = mu2 * mu2, mu12 = mu1 * mu2;
                float ssum = acc[u][2] - mu1s - mu2s;   // sigma1^2 + sigma2^2
                float s12  = acc[u][3] - mu12;
                float num = (2.f * mu12 + C1c) * (2.f * s12 + C2c);
                float den = (mu1s + mu2s + C1c) * (ssum + C2c);
                ssim_sum += num * __builtin_amdgcn_rcpf(den);
            }
        }
    }

    // ---- Block reduction, then hashed double atomics
    #pragma unroll
    for (int off = 32; off > 0; off >>= 1) {
        ssim_sum += __shfl_down(ssim_sum, off);
        l1_sum   += __shfl_down(l1_sum, off);
    }
    int wave = tid >> 6;
    if ((tid & 63) == 0) { red[wave] = ssim_sum; red[4 + wave] = l1_sum; }
    __syncthreads();
    if (tid == 0) {
        float s = red[0] + red[1] + red[2] + red[3];
        float l = red[4] + red[5] + red[6] + red[7];
        double* slot = accum + (size_t)(orig & (NSLOT - 1)) * 2;
        atomicAdd(&slot[0], (double)l);
        atomicAdd(&slot[1], (double)s);
    }
}

__global__ __launch_bounds__(NSLOT) void photo_final(
    const double* __restrict__ accum, float* __restrict__ out, double invN)
{
    __shared__ double sl[8], ss[8];
    int tid = threadIdx.x;
    double l = accum[tid * 2 + 0];
    double s = accum[tid * 2 + 1];
    #pragma unroll
    for (int off = 32; off > 0; off >>= 1) {
        l += __shfl_down(l, off);
        s += __shfl_down(s, off);
    }
    if ((tid & 63) == 0) { sl[tid >> 6] = l; ss[tid >> 6] = s; }
    __syncthreads();
    if (tid == 0) {
        double L = 0.0, S = 0.0;
        #pragma unroll
        for (int i = 0; i < NSLOT / 64; ++i) { L += sl[i]; S += ss[i]; }
        double l1    = L * invN;
        double ssim  = S * invN;
        double dssim = (1.0 - ssim) * 0.5;
        out[0] = (float)(0.8 * l1 + 0.2 * dssim);
        out[1] = (float)l1;
        out[2] = (float)dssim;
    }
}

extern "C" void kernel_launch(void* const* d_in, const int* in_sizes, int n_in,
                              void* d_out, int out_size, void* d_ws, size_t ws_size,
                              hipStream_t stream)
{
    const int H = 1080, W = 1920, C = 3;
    const float* x = (const float*)d_in[0];
    const float* y = (const float*)d_in[1];
    int B = in_sizes[0] / (H * W * C);

    double* accum = (double*)d_ws;
    hipMemsetAsync(d_ws, 0, NSLOT * 2 * sizeof(double), stream);

    dim3 grid(GX, GY, B);
    int nwg = GX * GY * B;
    photo_main<<<grid, dim3(256), 0, stream>>>(x, y, accum, B, nwg);

    double invN = 1.0 / ((double)B * H * W * C);
    photo_final<<<1, NSLOT, 0, stream>>>(accum, (float*)d_out, invN);
}

// Round 9
// 107.006 us; speedup vs baseline: 2.6473x; 2.6473x over previous
//
#include <hip/hip_runtime.h>
#include <hip/hip_fp16.h>

// PhotometricLoss: total = 0.8*L1 + 0.2*DSSIM; fused separable 11x11 Gaussian
// SSIM, SAME zero padding. Inputs BHWC fp32 (B=4,H=1080,W=1920,C=3).
// R9: R8's uint4 plane-interleaved layout WITHOUT the spill: two-phase alias
// schedule. hcT2 (HCS=21, 10752B) aliases sP4 rows 0..30 only. Phase A: 256
// items (src rows 0..31), ONE item/thread, held state = 2 uint4 (8 VGPR),
// barrier, write. Phase B: 80 items (src rows 32..41, beyond the aliased
// region), streaming, no held state. LDS 14.8KB -> 8 blocks/CU.

typedef _Float16 h2_t __attribute__((ext_vector_type(2)));

#define TW 32
#define TH 32
#define IH 42         // tile rows incl halo
#define NPAIR 21      // column pairs (42 cols)
#define SPW 22        // sP4 row stride in uint4 (352B rows)
#define HCS 21        // hcT2 col stride in uint4 (336B: even b128 bank coverage)
#define NSLOT 512

#define HH 1080
#define WW 1920
#define GX 180        // (WW/TW)*3 channels
#define GY 34         // ceil(HH/TH)

// Gaussian(sigma=1.5, 11 taps), normalized; matches fp32 reference within ~2e-7
static constexpr float G[11] = {
    0.00102838f, 0.00759876f, 0.03600077f, 0.10936069f, 0.21300554f,
    0.26601174f, 0.21300554f, 0.10936069f, 0.03600077f, 0.00759876f,
    0.00102838f};

#define WV(m) (((m) >= 0 && (m) <= 10) ? G[((m) < 0) ? 0 : (((m) > 10) ? 10 : (m))] : 0.0f)

struct f4u { float x, y, z, w; } __attribute__((packed, aligned(4)));

__device__ __forceinline__ unsigned short f2hbits(float x) {
    return __half_as_ushort(__float2half(x));
}
__device__ __forceinline__ unsigned int pkrtz(float a, float b) {
    return __builtin_bit_cast(unsigned int, __builtin_amdgcn_cvt_pkrtz(a, b));
}
__device__ __forceinline__ float dot2h(unsigned int a, unsigned int b, float c) {
#if __has_builtin(__builtin_amdgcn_fdot2)
    return __builtin_amdgcn_fdot2(__builtin_bit_cast(h2_t, a),
                                  __builtin_bit_cast(h2_t, b), c, false);
#else
    h2_t ah = __builtin_bit_cast(h2_t, a), bh = __builtin_bit_cast(h2_t, b);
    return c + (float)ah[0] * (float)bh[0] + (float)ah[1] * (float)bh[1];
#endif
}

// h-pass item = (row-pair rp, output cols 2*p0, 2*p0+1), all 4 planes.
// Reads 2 rows x 6 uint4, returns 2 uint4 packed for hcT2 (e0,e1 halves
// per plane component).
__device__ __forceinline__ void h_item2p(const uint4* __restrict__ sP4,
                                         int rp, int p0, uint4 o[2]) {
    float a[2][2][4];
    #pragma unroll
    for (int e = 0; e < 2; ++e)
        #pragma unroll
        for (int u = 0; u < 2; ++u)
            #pragma unroll
            for (int q = 0; q < 4; ++q) a[e][u][q] = 0.f;
    #pragma unroll
    for (int e = 0; e < 2; ++e) {
        const uint4* sp = sP4 + (2 * rp + e) * SPW + p0;
        uint4 v[6];
        #pragma unroll
        for (int p = 0; p < 6; ++p) v[p] = sp[p];
        #pragma unroll
        for (int u = 0; u < 2; ++u) {
            #pragma unroll
            for (int p = 0; p < 6; ++p) {
                const float w0 = WV(2 * p - u), w1 = WV(2 * p + 1 - u);
                if (w0 != 0.f || w1 != 0.f) {
                    const unsigned gwc = (unsigned)f2hbits(w0) |
                                         ((unsigned)f2hbits(w1) << 16);
                    a[e][u][0] = dot2h(v[p].x, gwc, a[e][u][0]);
                    a[e][u][1] = dot2h(v[p].y, gwc, a[e][u][1]);
                    a[e][u][2] = dot2h(v[p].z, gwc, a[e][u][2]);
                    a[e][u][3] = dot2h(v[p].w, gwc, a[e][u][3]);
                }
            }
        }
    }
    #pragma unroll
    for (int u = 0; u < 2; ++u) {
        o[u].x = pkrtz(a[0][u][0], a[1][u][0]);
        o[u].y = pkrtz(a[0][u][1], a[1][u][1]);
        o[u].z = pkrtz(a[0][u][2], a[1][u][2]);
        o[u].w = pkrtz(a[0][u][3], a[1][u][3]);
    }
}

__global__ __launch_bounds__(256, 8) void photo_main(
    const float* __restrict__ xin, const float* __restrict__ yin,
    double* __restrict__ accum, int B, int nwg)
{
    __shared__ uint4 sP4[IH * SPW];   // 14784 B; hcT2 aliases bytes 0..10751
    __shared__ float red[8];

    // ---- bijective XCD swizzle (nwg % 8 == 0), channel fastest in x
    int orig = blockIdx.x + GX * (blockIdx.y + GY * blockIdx.z);
    int nid = ((nwg & 7) == 0) ? ((orig & 7) * (nwg >> 3) + (orig >> 3)) : orig;
    int bx   = nid % GX;
    int rest = nid / GX;
    int by   = rest % GY;
    int b    = rest / GY;
    int c    = bx % 3;
    int tx   = bx / 3;
    const int row0 = by * TH, col0 = tx * TW;
    const int tid  = threadIdx.x;
    const int imgbase = b * (HH * WW * 3) + c;

    // ---- Phase 1a: stage 4 packed fp16 moment planes {x,y,x2+y2,xy} as ONE
    // uint4 per (row, col-pair); fold L1 over the central 32x32.
    float l1_sum = 0.f;
    const bool interior = (tx >= 1) && (tx <= 58) && (by >= 1) && (by <= 32);
    if (interior) {
        for (int i = tid; i < IH * NPAIR; i += 256) {
            int r  = i / NPAIR;
            int pc = i - r * NPAIR;
            int gr  = row0 - 5 + r;
            int gc0 = col0 - 5 + 2 * pc;
            int base = imgbase + (gr * WW + gc0) * 3;
            f4u vx = *(const f4u*)&xin[base];     // x0 = .x, x1 = .w (stride-3)
            f4u vy = *(const f4u*)&yin[base];
            float x0 = vx.x, x1 = vx.w, y0 = vy.x, y1 = vy.w;
            uint4 w;
            w.x = pkrtz(x0, x1);
            w.y = pkrtz(y0, y1);
            w.z = pkrtz(fmaf(x0, x0, y0 * y0), fmaf(x1, x1, y1 * y1));
            w.w = pkrtz(x0 * y0, x1 * y1);
            sP4[r * SPW + pc] = w;
            if (r >= 5 && r < 5 + TH) {
                if (pc >= 3 && pc <= 18) l1_sum += fabsf(x0 - y0);
                if (pc >= 2 && pc <= 17) l1_sum += fabsf(x1 - y1);
            }
        }
    } else {
        #pragma unroll 1
        for (int i = tid; i < IH * NPAIR; i += 256) {
            int r  = i / NPAIR;
            int pc = i - r * NPAIR;
            int gr  = row0 - 5 + r;
            int gc0 = col0 - 5 + 2 * pc;
            bool rin = (unsigned)gr < (unsigned)HH;
            bool c0  = rin && ((unsigned)gc0       < (unsigned)WW);
            bool c1  = rin && ((unsigned)(gc0 + 1) < (unsigned)WW);
            int base = imgbase + (gr * WW + gc0) * 3;
            float x0 = 0.f, x1 = 0.f, y0 = 0.f, y1 = 0.f;
            if (c0) { x0 = xin[base];     y0 = yin[base]; }
            if (c1) { x1 = xin[base + 3]; y1 = yin[base + 3]; }
            uint4 w;
            w.x = pkrtz(x0, x1);
            w.y = pkrtz(y0, y1);
            w.z = pkrtz(fmaf(x0, x0, y0 * y0), fmaf(x1, x1, y1 * y1));
            w.w = pkrtz(x0 * y0, x1 * y1);
            sP4[r * SPW + pc] = w;
            if (r >= 5 && r < 5 + TH) {
                if (c0 && pc >= 3 && pc <= 18) l1_sum += fabsf(x0 - y0);
                if (c1 && pc >= 2 && pc <= 17) l1_sum += fabsf(x1 - y1);
            }
        }
    }
    __syncthreads();

    // ---- Phase 1b, two-phase alias schedule.
    // hcT2 = 32 cols x HCS(21) uint4 = 10752 B = sP4 rows 0..30 (partial 30).
    // Phase A: items rp 0..15 (src rows 0..31), one per thread, 8 VGPR held.
    // Phase B: items rp 16..20 (src rows 32..41 at offsets >= 11264: never
    // overwritten), threads 0..79, streaming.
    uint4* hcT2 = (uint4*)sP4;
    {
        int rpA = tid >> 4, p0A = tid & 15;
        uint4 oA[2];
        h_item2p(sP4, rpA, p0A, oA);
        __syncthreads();                       // all rows 0..31 consumed
        hcT2[(2 * p0A + 0) * HCS + rpA] = oA[0];
        hcT2[(2 * p0A + 1) * HCS + rpA] = oA[1];
        if (tid < 80) {                        // 5 row-pairs x 16 col-groups
            int rpB = 16 + (tid >> 4), p0B = tid & 15;
            uint4 oB[2];
            h_item2p(sP4, rpB, p0B, oB);
            hcT2[(2 * p0B + 0) * HCS + rpB] = oB[0];
            hcT2[(2 * p0B + 1) * HCS + rpB] = oB[1];
        }
        __syncthreads();
    }

    // ---- Phase 2: vertical conv via dot2; each b128 read = one row-pair of
    // all 4 planes, dot2-ready.
    const float C1c = 1e-4f, C2c = 9e-4f;
    float ssim_sum = 0.f;
    {
        int cc = tid & 31;
        int rb = (tid >> 5) << 2;          // output row base within tile
        const uint4* hp = hcT2 + cc * HCS + (rb >> 1);
        uint4 v[7];
        #pragma unroll
        for (int p = 0; p < 7; ++p) v[p] = hp[p];
        float acc[4][4];                   // [u][q]
        #pragma unroll
        for (int u = 0; u < 4; ++u)
            #pragma unroll
            for (int q = 0; q < 4; ++q) acc[u][q] = 0.f;
        #pragma unroll
        for (int u = 0; u < 4; ++u) {
            #pragma unroll
            for (int p = 0; p < 7; ++p) {
                const float w0 = WV(2 * p - u), w1 = WV(2 * p + 1 - u);
                if (w0 != 0.f || w1 != 0.f) {
                    const unsigned gwc = (unsigned)f2hbits(w0) |
                                         ((unsigned)f2hbits(w1) << 16);
                    acc[u][0] = dot2h(v[p].x, gwc, acc[u][0]);
                    acc[u][1] = dot2h(v[p].y, gwc, acc[u][1]);
                    acc[u][2] = dot2h(v[p].z, gwc, acc[u][2]);
                    acc[u][3] = dot2h(v[p].w, gwc, acc[u][3]);
                }
            }
        }
        #pragma unroll
        for (int u = 0; u < 4; ++u) {
            int gr = row0 + rb + u;
            if (gr < HH) {                 // cols always in range (WW % 32 == 0)
                float mu1 = acc[u][0], mu2 = acc[u][1];
                float mu1s = mu1 * mu1, mu2s = mu2 * mu2, mu12 = mu1 * mu2;
                float ssum = acc[u][2] - mu1s - mu2s;   // sigma1^2 + sigma2^2
                float s12  = acc[u][3] - mu12;
                float num = (2.f * mu12 + C1c) * (2.f * s12 + C2c);
                float den = (mu1s + mu2s + C1c) * (ssum + C2c);
                ssim_sum += num * __builtin_amdgcn_rcpf(den);
            }
        }
    }

    // ---- Block reduction, then hashed double atomics
    #pragma unroll
    for (int off = 32; off > 0; off >>= 1) {
        ssim_sum += __shfl_down(ssim_sum, off);
        l1_sum   += __shfl_down(l1_sum, off);
    }
    int wave = tid >> 6;
    if ((tid & 63) == 0) { red[wave] = ssim_sum; red[4 + wave] = l1_sum; }
    __syncthreads();
    if (tid == 0) {
        float s = red[0] + red[1] + red[2] + red[3];
        float l = red[4] + red[5] + red[6] + red[7];
        double* slot = accum + (size_t)(orig & (NSLOT - 1)) * 2;
        atomicAdd(&slot[0], (double)l);
        atomicAdd(&slot[1], (double)s);
    }
}

__global__ __launch_bounds__(NSLOT) void photo_final(
    const double* __restrict__ accum, float* __restrict__ out, double invN)
{
    __shared__ double sl[8], ss[8];
    int tid = threadIdx.x;
    double l = accum[tid * 2 + 0];
    double s = accum[tid * 2 + 1];
    #pragma unroll
    for (int off = 32; off > 0; off >>= 1) {
        l += __shfl_down(l, off);
        s += __shfl_down(s, off);
    }
    if ((tid & 63) == 0) { sl[tid >> 6] = l; ss[tid >> 6] = s; }
    __syncthreads();
    if (tid == 0) {
        double L = 0.0, S = 0.0;
        #pragma unroll
        for (int i = 0; i < NSLOT / 64; ++i) { L += sl[i]; S += ss[i]; }
        double l1    = L * invN;
        double ssim  = S * invN;
        double dssim = (1.0 - ssim) * 0.5;
        out[0] = (float)(0.8 * l1 + 0.2 * dssim);
        out[1] = (float)l1;
        out[2] = (float)dssim;
    }
}

extern "C" void kernel_launch(void* const* d_in, const int* in_sizes, int n_in,
                              void* d_out, int out_size, void* d_ws, size_t ws_size,
                              hipStream_t stream)
{
    const int H = 1080, W = 1920, C = 3;
    const float* x = (const float*)d_in[0];
    const float* y = (const float*)d_in[1];
    int B = in_sizes[0] / (H * W * C);

    double* accum = (double*)d_ws;
    hipMemsetAsync(d_ws, 0, NSLOT * 2 * sizeof(double), stream);

    dim3 grid(GX, GY, B);
    int nwg = GX * GY * B;
    photo_main<<<grid, dim3(256), 0, stream>>>(x, y, accum, B, nwg);

    double invN = 1.0 / ((double)B * H * W * C);
    photo_final<<<1, NSLOT, 0, stream>>>(accum, (float*)d_out, invN);
}

// Round 11
// 90.581 us; speedup vs baseline: 3.1274x; 1.1813x over previous
//
#include <hip/hip_runtime.h>
#include <hip/hip_fp16.h>

// PhotometricLoss: total = 0.8*L1 + 0.2*DSSIM; fused separable 11x11 Gaussian
// SSIM, SAME zero padding. Inputs BHWC fp32 (B=4,H=1080,W=1920,C=3).
// R11 (= R10 + host-pass compile fix): MFMA banded-GEMM conv. h-pass
// HC = S x W2, v-pass OUT = Wv x HC via v_mfma_f32_16x16x16_f16; W fragments
// are constexpr per-lane tables; h-pass D-frag == v-pass B-frag layout ->
// register chaining, no LDS round trip. One wave per moment plane
// {x, y, x2+y2, xy}. sV f32 exchange for SSIM.

typedef __fp16 hf4 __attribute__((ext_vector_type(4)));
typedef float f32x4 __attribute__((ext_vector_type(4)));

#define TW 32
#define TH 32
#define IH 42         // staged real rows (rows 42..47 zero)
#define NPAIR 21
#define SROW 52       // staged row stride in halves (104 B, b64-aligned)
#define NSLOT 512
#define HH 1080
#define WW 1920
#define GX 180
#define GY 34

// Gaussian(sigma=1.5, 11 taps), normalized; matches fp32 reference within ~2e-7
static constexpr float G[11] = {
    0.00102838f, 0.00759876f, 0.03600077f, 0.10936069f, 0.21300554f,
    0.26601174f, 0.21300554f, 0.10936069f, 0.03600077f, 0.00759876f,
    0.00102838f};

// ---- constexpr f32 -> f16 bits (RNE); G values are all f16-normal
constexpr unsigned short f2h_cx(float f) {
    unsigned u = __builtin_bit_cast(unsigned, f);
    if ((u & 0x7fffffffu) == 0) return 0;
    int e = (int)((u >> 23) & 0xff) - 127 + 15;
    unsigned man = u & 0x7fffffu;
    unsigned m = man >> 13;
    unsigned rest = man & 0x1fffu;
    if (rest > 0x1000u || (rest == 0x1000u && (m & 1u))) {
        if (++m == 0x400u) { m = 0; ++e; }
    }
    return (unsigned short)((e << 10) | m);
}
constexpr float Gf(int d) { return (d >= 0 && d <= 10) ? G[d] : 0.0f; }
constexpr unsigned wpk(int d) {
    return (unsigned)f2h_cx(Gf(d)) | ((unsigned)f2h_cx(Gf(d + 1)) << 16);
}
// Band-matrix fragment table: for lane l, tile-delta dl (= delta+1 in 0..3),
// halves i=0..3 are g[16*(dl-1) + 4*(l>>4) - (l&15) + i]. Serves BOTH
// h-pass B-frags (dl = k2-n+1) and v-pass A-frags (dl = t-u+1).
struct WTbl {
    unsigned long long v[4][64];
    constexpr WTbl() : v{} {
        for (int dl = 0; dl < 4; ++dl)
            for (int l = 0; l < 64; ++l) {
                int d0 = 16 * (dl - 1) + ((l >> 4) << 2) - (l & 15);
                v[dl][l] = (unsigned long long)wpk(d0) |
                           ((unsigned long long)wpk(d0 + 2) << 32);
            }
    }
};
__device__ const WTbl WT{};

struct f4u { float x, y, z, w; } __attribute__((packed, aligned(4)));

__device__ __forceinline__ unsigned int pkrtz(float a, float b) {
    return __builtin_bit_cast(unsigned int, __builtin_amdgcn_cvt_pkrtz(a, b));
}
__device__ __forceinline__ f32x4 mfma16(hf4 a, hf4 b, f32x4 c) {
#if defined(__HIP_DEVICE_COMPILE__)
    return __builtin_amdgcn_mfma_f32_16x16x16f16(a, b, c, 0, 0, 0);
#else
    (void)a; (void)b;
    return c;   // host pass: never executed, just needs to parse
#endif
}

__global__ __launch_bounds__(256, 6) void photo_main(
    const float* __restrict__ xin, const float* __restrict__ yin,
    double* __restrict__ accum, int B, int nwg)
{
    __shared__ __align__(16) unsigned char smem[16384];
    __shared__ float red[8];
    unsigned short* sXh = (unsigned short*)smem;               // [48][SROW] halves
    unsigned short* sYh = (unsigned short*)(smem + 48 * SROW * 2);
    unsigned* sXu = (unsigned*)sXh;
    unsigned* sYu = (unsigned*)sYh;
    float* sV = (float*)smem;    // [4][1024] f32, aliased AFTER h-pass reads

    // ---- bijective XCD swizzle (nwg % 8 == 0), channel fastest in x
    int orig = blockIdx.x + GX * (blockIdx.y + GY * blockIdx.z);
    int nid = ((nwg & 7) == 0) ? ((orig & 7) * (nwg >> 3) + (orig >> 3)) : orig;
    int bx   = nid % GX;
    int rest = nid / GX;
    int by   = rest % GY;
    int b    = rest / GY;
    int c    = bx % 3;
    int tx   = bx / 3;
    const int row0 = by * TH, col0 = tx * TW;
    const int tid  = threadIdx.x;
    const int lane = tid & 63;
    const int wid  = tid >> 6;          // wave id == moment plane q
    const int imgbase = b * (HH * WW * 3) + c;

    // ---- zero-fill staging region (rows 42..47 & pads must be 0, not NaN)
    {
        uint4 z = make_uint4(0, 0, 0, 0);
        #pragma unroll
        for (int j = 0; j < 3; ++j) {
            int idx = tid + j * 256;
            if (idx < 624) ((uint4*)smem)[idx] = z;
        }
    }
    __syncthreads();

    // ---- Phase 1a: stage x,y as packed f16 pairs; fold L1 over central 32x32
    float l1_sum = 0.f;
    const bool interior = (tx >= 1) && (tx <= 58) && (by >= 1) && (by <= 32);
    if (interior) {
        for (int i = tid; i < IH * NPAIR; i += 256) {
            int r  = i / NPAIR;
            int pc = i - r * NPAIR;
            int gr  = row0 - 5 + r;
            int gc0 = col0 - 5 + 2 * pc;
            int base = imgbase + (gr * WW + gc0) * 3;
            f4u vx = *(const f4u*)&xin[base];     // x0 = .x, x1 = .w (stride-3)
            f4u vy = *(const f4u*)&yin[base];
            float x0 = vx.x, x1 = vx.w, y0 = vy.x, y1 = vy.w;
            sXu[r * (SROW / 2) + pc] = pkrtz(x0, x1);
            sYu[r * (SROW / 2) + pc] = pkrtz(y0, y1);
            if (r >= 5 && r < 5 + TH) {
                if (pc >= 3 && pc <= 18) l1_sum += fabsf(x0 - y0);
                if (pc >= 2 && pc <= 17) l1_sum += fabsf(x1 - y1);
            }
        }
    } else {
        #pragma unroll 1
        for (int i = tid; i < IH * NPAIR; i += 256) {
            int r  = i / NPAIR;
            int pc = i - r * NPAIR;
            int gr  = row0 - 5 + r;
            int gc0 = col0 - 5 + 2 * pc;
            bool rin = (unsigned)gr < (unsigned)HH;
            bool c0  = rin && ((unsigned)gc0       < (unsigned)WW);
            bool c1  = rin && ((unsigned)(gc0 + 1) < (unsigned)WW);
            int base = imgbase + (gr * WW + gc0) * 3;
            float x0 = 0.f, x1 = 0.f, y0 = 0.f, y1 = 0.f;
            if (c0) { x0 = xin[base];     y0 = yin[base]; }
            if (c1) { x1 = xin[base + 3]; y1 = yin[base + 3]; }
            sXu[r * (SROW / 2) + pc] = pkrtz(x0, x1);
            sYu[r * (SROW / 2) + pc] = pkrtz(y0, y1);
            if (r >= 5 && r < 5 + TH) {
                if (c0 && pc >= 3 && pc <= 18) l1_sum += fabsf(x0 - y0);
                if (c1 && pc >= 2 && pc <= 17) l1_sum += fabsf(x1 - y1);
            }
        }
    }
    __syncthreads();

    // ---- W fragments (4 tile-deltas, shared by h-pass B and v-pass A)
    hf4 wf[4];
    #pragma unroll
    for (int dl = 0; dl < 4; ++dl)
        wf[dl] = __builtin_bit_cast(hf4, WT.v[dl][lane]);

    // ---- h-pass: HC[48x32] = S x W2 per plane (wave = plane wid).
    // A-frag: S[16t + (l&15)][16k2 + 4*(l>>4) + i]; D rows 16t+4*(l>>4)+reg
    // == v-pass B-frag k -> keep in registers (bfr).
    const int lr = lane & 15;
    const int lk = (lane >> 4) << 2;
    hf4 bfr[3][2];
    #pragma unroll
    for (int t = 0; t < 3; ++t) {
        f32x4 d0 = {0.f, 0.f, 0.f, 0.f}, d1 = {0.f, 0.f, 0.f, 0.f};
        #pragma unroll
        for (int k2 = 0; k2 < 3; ++k2) {
            int off = (16 * t + lr) * SROW + 16 * k2 + lk;
            uint2 rx = *(const uint2*)(sXh + off);
            hf4 a;
            if (wid == 0) {
                a = __builtin_bit_cast(hf4, rx);
            } else if (wid == 1) {
                uint2 ry = *(const uint2*)(sYh + off);
                a = __builtin_bit_cast(hf4, ry);
            } else {
                uint2 ry = *(const uint2*)(sYh + off);
                hf4 xv = __builtin_bit_cast(hf4, rx);
                hf4 yv = __builtin_bit_cast(hf4, ry);
                a = (wid == 2) ? (hf4)(xv * xv + yv * yv) : (hf4)(xv * yv);
            }
            d0 = mfma16(a, wf[k2 + 1], d0);      // n = 0
            d1 = mfma16(a, wf[k2],     d1);      // n = 1
        }
        bfr[t][0] = __builtin_convertvector(d0, hf4);
        bfr[t][1] = __builtin_convertvector(d1, hf4);
    }
    __syncthreads();    // staging reads complete; sV may now alias smem

    // ---- v-pass: OUT = Wv x HC, registers only
    f32x4 vacc[2][2];
    #pragma unroll
    for (int u = 0; u < 2; ++u)
        #pragma unroll
        for (int n = 0; n < 2; ++n)
            vacc[u][n] = (f32x4){0.f, 0.f, 0.f, 0.f};
    #pragma unroll
    for (int u = 0; u < 2; ++u)
        #pragma unroll
        for (int t = 0; t < 3; ++t) {
            vacc[u][0] = mfma16(wf[t - u + 1], bfr[t][0], vacc[u][0]);
            vacc[u][1] = mfma16(wf[t - u + 1], bfr[t][1], vacc[u][1]);
        }

    // ---- write plane results to sV[q][1024] (XOR-swizzled, conflict-free)
    {
        float* sVq = sV + wid * 1024;
        #pragma unroll
        for (int u = 0; u < 2; ++u)
            #pragma unroll
            for (int g2 = 0; g2 < 4; ++g2) {
                int R = 16 * u + lk + g2;
                int swz = (R >> 2) & 3;
                #pragma unroll
                for (int n = 0; n < 2; ++n) {
                    int idx = (R * 32 + (16 * n + lr)) ^ swz;
                    sVq[idx] = vacc[u][n][g2];
                }
            }
    }
    __syncthreads();

    // ---- SSIM from the 4 planes, 4 px per thread
    const float C1c = 1e-4f, C2c = 9e-4f;
    float ssim_sum = 0.f;
    #pragma unroll
    for (int j = 0; j < 4; ++j) {
        int px = j * 256 + tid;
        int R = px >> 5;
        if (row0 + R < HH) {
            int idx = px ^ ((px >> 7) & 3);
            float mu1 = sV[idx];
            float mu2 = sV[1024 + idx];
            float s2s = sV[2048 + idx];
            float s12 = sV[3072 + idx];
            float mu1s = mu1 * mu1, mu2s = mu2 * mu2, mu12 = mu1 * mu2;
            float ssum = s2s - mu1s - mu2s;      // sigma1^2 + sigma2^2
            float sxy  = s12 - mu12;
            float num = (2.f * mu12 + C1c) * (2.f * sxy + C2c);
            float den = (mu1s + mu2s + C1c) * (ssum + C2c);
            ssim_sum += num * __builtin_amdgcn_rcpf(den);
        }
    }

    // ---- Block reduction, then hashed double atomics
    #pragma unroll
    for (int off = 32; off > 0; off >>= 1) {
        ssim_sum += __shfl_down(ssim_sum, off);
        l1_sum   += __shfl_down(l1_sum, off);
    }
    if ((tid & 63) == 0) { red[wid] = ssim_sum; red[4 + wid] = l1_sum; }
    __syncthreads();
    if (tid == 0) {
        float s = red[0] + red[1] + red[2] + red[3];
        float l = red[4] + red[5] + red[6] + red[7];
        double* slot = accum + (size_t)(orig & (NSLOT - 1)) * 2;
        atomicAdd(&slot[0], (double)l);
        atomicAdd(&slot[1], (double)s);
    }
}

__global__ __launch_bounds__(NSLOT) void photo_final(
    const double* __restrict__ accum, float* __restrict__ out, double invN)
{
    __shared__ double sl[8], ss[8];
    int tid = threadIdx.x;
    double l = accum[tid * 2 + 0];
    double s = accum[tid * 2 + 1];
    #pragma unroll
    for (int off = 32; off > 0; off >>= 1) {
        l += __shfl_down(l, off);
        s += __shfl_down(s, off);
    }
    if ((tid & 63) == 0) { sl[tid >> 6] = l; ss[tid >> 6] = s; }
    __syncthreads();
    if (tid == 0) {
        double L = 0.0, S = 0.0;
        #pragma unroll
        for (int i = 0; i < NSLOT / 64; ++i) { L += sl[i]; S += ss[i]; }
        double l1    = L * invN;
        double ssim  = S * invN;
        double dssim = (1.0 - ssim) * 0.5;
        out[0] = (float)(0.8 * l1 + 0.2 * dssim);
        out[1] = (float)l1;
        out[2] = (float)dssim;
    }
}

extern "C" void kernel_launch(void* const* d_in, const int* in_sizes, int n_in,
                              void* d_out, int out_size, void* d_ws, size_t ws_size,
                              hipStream_t stream)
{
    const int H = 1080, W = 1920, C = 3;
    const float* x = (const float*)d_in[0];
    const float* y = (const float*)d_in[1];
    int B = in_sizes[0] / (H * W * C);

    double* accum = (double*)d_ws;
    (void)hipMemsetAsync(d_ws, 0, NSLOT * 2 * sizeof(double), stream);

    dim3 grid(GX, GY, B);
    int nwg = GX * GY * B;
    photo_main<<<grid, dim3(256), 0, stream>>>(x, y, accum, B, nwg);

    double invN = 1.0 / ((double)B * H * W * C);
    photo_final<<<1, NSLOT, 0, stream>>>(accum, (float*)d_out, invN);
}

// Round 12
// 90.427 us; speedup vs baseline: 3.1327x; 1.0017x over previous
//
#include <hip/hip_runtime.h>
#include <hip/hip_fp16.h>

// PhotometricLoss: total = 0.8*L1 + 0.2*DSSIM; fused separable 11x11 Gaussian
// SSIM, SAME zero padding. Inputs BHWC fp32 (B=4,H=1080,W=1920,C=3).
// R12 (= R11 + occupancy/pack tune): MFMA banded-GEMM conv, one wave per
// moment plane {x, y, x2+y2, xy}; register-chained h->v pass.
// launch_bounds(256,8) -> 8 blocks/CU (VGPR 24, LDS 16.9KB allow it);
// f32x4->hf4 packing via 2x cvt_pkrtz instead of 4x scalar cvt.

typedef __fp16 hf4 __attribute__((ext_vector_type(4)));
typedef float f32x4 __attribute__((ext_vector_type(4)));

#define TW 32
#define TH 32
#define IH 42         // staged real rows (rows 42..47 zero)
#define NPAIR 21
#define SROW 52       // staged row stride in halves (104 B, keeps b64 alignment)
#define NSLOT 512
#define HH 1080
#define WW 1920
#define GX 180
#define GY 34

// Gaussian(sigma=1.5, 11 taps), normalized; matches fp32 reference within ~2e-7
static constexpr float G[11] = {
    0.00102838f, 0.00759876f, 0.03600077f, 0.10936069f, 0.21300554f,
    0.26601174f, 0.21300554f, 0.10936069f, 0.03600077f, 0.00759876f,
    0.00102838f};

// ---- constexpr f32 -> f16 bits (RNE); G values are all f16-normal
constexpr unsigned short f2h_cx(float f) {
    unsigned u = __builtin_bit_cast(unsigned, f);
    if ((u & 0x7fffffffu) == 0) return 0;
    int e = (int)((u >> 23) & 0xff) - 127 + 15;
    unsigned man = u & 0x7fffffu;
    unsigned m = man >> 13;
    unsigned rest = man & 0x1fffu;
    if (rest > 0x1000u || (rest == 0x1000u && (m & 1u))) {
        if (++m == 0x400u) { m = 0; ++e; }
    }
    return (unsigned short)((e << 10) | m);
}
constexpr float Gf(int d) { return (d >= 0 && d <= 10) ? G[d] : 0.0f; }
constexpr unsigned wpk(int d) {
    return (unsigned)f2h_cx(Gf(d)) | ((unsigned)f2h_cx(Gf(d + 1)) << 16);
}
// Band-matrix fragment table: for lane l, tile-delta dl (= delta+1 in 0..3),
// halves i=0..3 are g[16*(dl-1) + 4*(l>>4) - (l&15) + i]. Serves BOTH
// h-pass B-frags (dl = k2-n+1) and v-pass A-frags (dl = t-u+1).
struct WTbl {
    unsigned long long v[4][64];
    constexpr WTbl() : v{} {
        for (int dl = 0; dl < 4; ++dl)
            for (int l = 0; l < 64; ++l) {
                int d0 = 16 * (dl - 1) + ((l >> 4) << 2) - (l & 15);
                v[dl][l] = (unsigned long long)wpk(d0) |
                           ((unsigned long long)wpk(d0 + 2) << 32);
            }
    }
};
__device__ const WTbl WT{};

struct f4u { float x, y, z, w; } __attribute__((packed, aligned(4)));

__device__ __forceinline__ unsigned int pkrtz(float a, float b) {
    return __builtin_bit_cast(unsigned int, __builtin_amdgcn_cvt_pkrtz(a, b));
}
__device__ __forceinline__ hf4 pk4(const f32x4& d) {
    uint2 u = make_uint2(pkrtz(d[0], d[1]), pkrtz(d[2], d[3]));
    return __builtin_bit_cast(hf4, u);
}
__device__ __forceinline__ f32x4 mfma16(hf4 a, hf4 b, f32x4 c) {
#if defined(__HIP_DEVICE_COMPILE__)
    return __builtin_amdgcn_mfma_f32_16x16x16f16(a, b, c, 0, 0, 0);
#else
    (void)a; (void)b;
    return c;   // host pass: never executed, just needs to parse
#endif
}

__global__ __launch_bounds__(256, 8) void photo_main(
    const float* __restrict__ xin, const float* __restrict__ yin,
    double* __restrict__ accum, int B, int nwg)
{
    __shared__ __align__(16) unsigned char smem[16384];
    __shared__ float red[8];
    unsigned short* sXh = (unsigned short*)smem;               // [48][SROW] halves
    unsigned short* sYh = (unsigned short*)(smem + 48 * SROW * 2);
    unsigned* sXu = (unsigned*)sXh;
    unsigned* sYu = (unsigned*)sYh;
    float* sV = (float*)smem;    // [4][1024] f32, aliased AFTER h-pass reads

    // ---- bijective XCD swizzle (nwg % 8 == 0), channel fastest in x
    int orig = blockIdx.x + GX * (blockIdx.y + GY * blockIdx.z);
    int nid = ((nwg & 7) == 0) ? ((orig & 7) * (nwg >> 3) + (orig >> 3)) : orig;
    int bx   = nid % GX;
    int rest = nid / GX;
    int by   = rest % GY;
    int b    = rest / GY;
    int c    = bx % 3;
    int tx   = bx / 3;
    const int row0 = by * TH, col0 = tx * TW;
    const int tid  = threadIdx.x;
    const int lane = tid & 63;
    const int wid  = tid >> 6;          // wave id == moment plane q
    const int imgbase = b * (HH * WW * 3) + c;

    // ---- zero-fill staging region (rows 42..47 & pads must be 0, not NaN)
    {
        uint4 z = make_uint4(0, 0, 0, 0);
        #pragma unroll
        for (int j = 0; j < 3; ++j) {
            int idx = tid + j * 256;
            if (idx < 624) ((uint4*)smem)[idx] = z;
        }
    }
    __syncthreads();

    // ---- Phase 1a: stage x,y as packed f16 pairs; fold L1 over central 32x32
    float l1_sum = 0.f;
    const bool interior = (tx >= 1) && (tx <= 58) && (by >= 1) && (by <= 32);
    if (interior) {
        for (int i = tid; i < IH * NPAIR; i += 256) {
            int r  = i / NPAIR;
            int pc = i - r * NPAIR;
            int gr  = row0 - 5 + r;
            int gc0 = col0 - 5 + 2 * pc;
            int base = imgbase + (gr * WW + gc0) * 3;
            f4u vx = *(const f4u*)&xin[base];     // x0 = .x, x1 = .w (stride-3)
            f4u vy = *(const f4u*)&yin[base];
            float x0 = vx.x, x1 = vx.w, y0 = vy.x, y1 = vy.w;
            sXu[r * (SROW / 2) + pc] = pkrtz(x0, x1);
            sYu[r * (SROW / 2) + pc] = pkrtz(y0, y1);
            if (r >= 5 && r < 5 + TH) {
                if (pc >= 3 && pc <= 18) l1_sum += fabsf(x0 - y0);
                if (pc >= 2 && pc <= 17) l1_sum += fabsf(x1 - y1);
            }
        }
    } else {
        #pragma unroll 1
        for (int i = tid; i < IH * NPAIR; i += 256) {
            int r  = i / NPAIR;
            int pc = i - r * NPAIR;
            int gr  = row0 - 5 + r;
            int gc0 = col0 - 5 + 2 * pc;
            bool rin = (unsigned)gr < (unsigned)HH;
            bool c0  = rin && ((unsigned)gc0       < (unsigned)WW);
            bool c1  = rin && ((unsigned)(gc0 + 1) < (unsigned)WW);
            int base = imgbase + (gr * WW + gc0) * 3;
            float x0 = 0.f, x1 = 0.f, y0 = 0.f, y1 = 0.f;
            if (c0) { x0 = xin[base];     y0 = yin[base]; }
            if (c1) { x1 = xin[base + 3]; y1 = yin[base + 3]; }
            sXu[r * (SROW / 2) + pc] = pkrtz(x0, x1);
            sYu[r * (SROW / 2) + pc] = pkrtz(y0, y1);
            if (r >= 5 && r < 5 + TH) {
                if (c0 && pc >= 3 && pc <= 18) l1_sum += fabsf(x0 - y0);
                if (c1 && pc >= 2 && pc <= 17) l1_sum += fabsf(x1 - y1);
            }
        }
    }
    __syncthreads();

    // ---- W fragments (4 tile-deltas, shared by h-pass B and v-pass A)
    hf4 wf[4];
    #pragma unroll
    for (int dl = 0; dl < 4; ++dl)
        wf[dl] = __builtin_bit_cast(hf4, WT.v[dl][lane]);

    // ---- h-pass: HC[48x32] = S x W2 per plane (wave = plane wid).
    // A-frag: S[16t + (l&15)][16k2 + 4*(l>>4) + i]; D rows 16t+4*(l>>4)+reg
    // == v-pass B-frag k -> keep in registers (bfr).
    const int lr = lane & 15;
    const int lk = (lane >> 4) << 2;
    hf4 bfr[3][2];
    #pragma unroll
    for (int t = 0; t < 3; ++t) {
        f32x4 d0 = {0.f, 0.f, 0.f, 0.f}, d1 = {0.f, 0.f, 0.f, 0.f};
        #pragma unroll
        for (int k2 = 0; k2 < 3; ++k2) {
            int off = (16 * t + lr) * SROW + 16 * k2 + lk;
            uint2 rx = *(const uint2*)(sXh + off);
            hf4 a;
            if (wid == 0) {
                a = __builtin_bit_cast(hf4, rx);
            } else if (wid == 1) {
                uint2 ry = *(const uint2*)(sYh + off);
                a = __builtin_bit_cast(hf4, ry);
            } else {
                uint2 ry = *(const uint2*)(sYh + off);
                hf4 xv = __builtin_bit_cast(hf4, rx);
                hf4 yv = __builtin_bit_cast(hf4, ry);
                a = (wid == 2) ? (hf4)(xv * xv + yv * yv) : (hf4)(xv * yv);
            }
            d0 = mfma16(a, wf[k2 + 1], d0);      // n = 0
            d1 = mfma16(a, wf[k2],     d1);      // n = 1
        }
        bfr[t][0] = pk4(d0);
        bfr[t][1] = pk4(d1);
    }
    __syncthreads();    // staging reads complete; sV may now alias smem

    // ---- v-pass: OUT = Wv x HC, registers only
    f32x4 vacc[2][2];
    #pragma unroll
    for (int u = 0; u < 2; ++u)
        #pragma unroll
        for (int n = 0; n < 2; ++n)
            vacc[u][n] = (f32x4){0.f, 0.f, 0.f, 0.f};
    #pragma unroll
    for (int u = 0; u < 2; ++u)
        #pragma unroll
        for (int t = 0; t < 3; ++t) {
            vacc[u][0] = mfma16(wf[t - u + 1], bfr[t][0], vacc[u][0]);
            vacc[u][1] = mfma16(wf[t - u + 1], bfr[t][1], vacc[u][1]);
        }

    // ---- write plane results to sV[q][1024] (XOR-swizzled, conflict-free)
    {
        float* sVq = sV + wid * 1024;
        #pragma unroll
        for (int u = 0; u < 2; ++u)
            #pragma unroll
            for (int g2 = 0; g2 < 4; ++g2) {
                int R = 16 * u + lk + g2;
                int swz = (R >> 2) & 3;
                #pragma unroll
                for (int n = 0; n < 2; ++n) {
                    int idx = (R * 32 + (16 * n + lr)) ^ swz;
                    sVq[idx] = vacc[u][n][g2];
                }
            }
    }
    __syncthreads();

    // ---- SSIM from the 4 planes, 4 px per thread
    const float C1c = 1e-4f, C2c = 9e-4f;
    float ssim_sum = 0.f;
    #pragma unroll
    for (int j = 0; j < 4; ++j) {
        int px = j * 256 + tid;
        int R = px >> 5;
        if (row0 + R < HH) {
            int idx = px ^ ((px >> 7) & 3);
            float mu1 = sV[idx];
            float mu2 = sV[1024 + idx];
            float s2s = sV[2048 + idx];
            float s12 = sV[3072 + idx];
            float mu1s = mu1 * mu1, mu2s = mu2 * mu2, mu12 = mu1 * mu2;
            float ssum = s2s - mu1s - mu2s;      // sigma1^2 + sigma2^2
            float sxy  = s12 - mu12;
            float num = (2.f * mu12 + C1c) * (2.f * sxy + C2c);
            float den = (mu1s + mu2s + C1c) * (ssum + C2c);
            ssim_sum += num * __builtin_amdgcn_rcpf(den);
        }
    }

    // ---- Block reduction, then hashed double atomics
    #pragma unroll
    for (int off = 32; off > 0; off >>= 1) {
        ssim_sum += __shfl_down(ssim_sum, off);
        l1_sum   += __shfl_down(l1_sum, off);
    }
    if ((tid & 63) == 0) { red[wid] = ssim_sum; red[4 + wid] = l1_sum; }
    __syncthreads();
    if (tid == 0) {
        float s = red[0] + red[1] + red[2] + red[3];
        float l = red[4] + red[5] + red[6] + red[7];
        double* slot = accum + (size_t)(orig & (NSLOT - 1)) * 2;
        atomicAdd(&slot[0], (double)l);
        atomicAdd(&slot[1], (double)s);
    }
}

__global__ __launch_bounds__(NSLOT) void photo_final(
    const double* __restrict__ accum, float* __restrict__ out, double invN)
{
    __shared__ double sl[8], ss[8];
    int tid = threadIdx.x;
    double l = accum[tid * 2 + 0];
    double s = accum[tid * 2 + 1];
    #pragma unroll
    for (int off = 32; off > 0; off >>= 1) {
        l += __shfl_down(l, off);
        s += __shfl_down(s, off);
    }
    if ((tid & 63) == 0) { sl[tid >> 6] = l; ss[tid >> 6] = s; }
    __syncthreads();
    if (tid == 0) {
        double L = 0.0, S = 0.0;
        #pragma unroll
        for (int i = 0; i < NSLOT / 64; ++i) { L += sl[i]; S += ss[i]; }
        double l1    = L * invN;
        double ssim  = S * invN;
        double dssim = (1.0 - ssim) * 0.5;
        out[0] = (float)(0.8 * l1 + 0.2 * dssim);
        out[1] = (float)l1;
        out[2] = (float)dssim;
    }
}

extern "C" void kernel_launch(void* const* d_in, const int* in_sizes, int n_in,
                              void* d_out, int out_size, void* d_ws, size_t ws_size,
                              hipStream_t stream)
{
    const int H = 1080, W = 1920, C = 3;
    const float* x = (const float*)d_in[0];
    const float* y = (const float*)d_in[1];
    int B = in_sizes[0] / (H * W * C);

    double* accum = (double*)d_ws;
    (void)hipMemsetAsync(d_ws, 0, NSLOT * 2 * sizeof(double), stream);

    dim3 grid(GX, GY, B);
    int nwg = GX * GY * B;
    photo_main<<<grid, dim3(256), 0, stream>>>(x, y, accum, B, nwg);

    double invN = 1.0 / ((double)B * H * W * C);
    photo_final<<<1, NSLOT, 0, stream>>>(accum, (float*)d_out, invN);
}